// Round 8
// baseline (283.795 us; speedup 1.0000x reference)
//
#include <hip/hip_runtime.h>

constexpr int C    = 21;
constexpr int CC   = C * C;    // 441 bins
constexpr int CCP  = 448;      // padded partial row (multiple of 64)
constexpr int NSUB = 16;       // sub-histogram per half-wave (512 thr = 16 half-waves)
constexpr int BLK  = 512;
constexpr int CTR_STRIDE = 16; // spread per-batch counters 64 B apart
constexpr size_t CTR_BYTES = 512;

// ---------- fused: per-block partial histograms + last-block finalize ----------
// NOTE: GRID-STRIDE access (stride = blocks_per_batch*BLK). Round 7 proved that
// block-contiguous 128KB chunks cause HBM channel camping (350 GB/s, 8x slower):
// at equal phase all blocks share the same low address bits -> same channel.
__global__ __launch_bounds__(BLK, 4)
void conf_hist_fused(const int* __restrict__ yp,
                     const int* __restrict__ y,
                     unsigned int* __restrict__ partial,   // [nblocks][CCP]
                     unsigned int* __restrict__ counters,  // [B*CTR_STRIDE]
                     float* __restrict__ out,
                     int n_per_batch,
                     int blocks_per_batch) {
    __shared__ unsigned int hist[NSUB][CC];   // 28 KiB
    __shared__ int is_last;

    const int tid = threadIdx.x;
    for (int i = tid; i < (NSUB * CC) / 4; i += BLK)
        ((uint4*)hist)[i] = make_uint4(0u, 0u, 0u, 0u);
    __syncthreads();

    const int b   = blockIdx.x / blocks_per_batch;
    const int blk = blockIdx.x - b * blocks_per_batch;

    const int4* yp4 = (const int4*)(yp + (size_t)b * n_per_batch);
    const int4* y4  = (const int4*)(y  + (size_t)b * n_per_batch);
    const int n4     = n_per_batch >> 2;
    const int stride = blocks_per_batch * BLK;

    unsigned int* h = hist[tid >> 5];   // private per half-wave

    int i = blk * BLK + tid;
    for (; i + 3 * stride < n4; i += 4 * stride) {
        int4 a0 = yp4[i];
        int4 a1 = yp4[i + stride];
        int4 a2 = yp4[i + 2 * stride];
        int4 a3 = yp4[i + 3 * stride];
        int4 c0 = y4[i];
        int4 c1 = y4[i + stride];
        int4 c2 = y4[i + 2 * stride];
        int4 c3 = y4[i + 3 * stride];

        atomicAdd(&h[a0.x * C + c0.x], 1u);
        atomicAdd(&h[a0.y * C + c0.y], 1u);
        atomicAdd(&h[a0.z * C + c0.z], 1u);
        atomicAdd(&h[a0.w * C + c0.w], 1u);
        atomicAdd(&h[a1.x * C + c1.x], 1u);
        atomicAdd(&h[a1.y * C + c1.y], 1u);
        atomicAdd(&h[a1.z * C + c1.z], 1u);
        atomicAdd(&h[a1.w * C + c1.w], 1u);
        atomicAdd(&h[a2.x * C + c2.x], 1u);
        atomicAdd(&h[a2.y * C + c2.y], 1u);
        atomicAdd(&h[a2.z * C + c2.z], 1u);
        atomicAdd(&h[a2.w * C + c2.w], 1u);
        atomicAdd(&h[a3.x * C + c3.x], 1u);
        atomicAdd(&h[a3.y * C + c3.y], 1u);
        atomicAdd(&h[a3.z * C + c3.z], 1u);
        atomicAdd(&h[a3.w * C + c3.w], 1u);
    }
    for (; i < n4; i += stride) {
        int4 a = yp4[i];
        int4 c = y4[i];
        atomicAdd(&h[a.x * C + c.x], 1u);
        atomicAdd(&h[a.y * C + c.y], 1u);
        atomicAdd(&h[a.z * C + c.z], 1u);
        atomicAdd(&h[a.w * C + c.w], 1u);
    }
    __syncthreads();

    // coalesced store of this block's 441 counts
    unsigned int* pb = partial + (size_t)blockIdx.x * CCP;
    for (int j = tid; j < CC; j += BLK) {
        unsigned int s = 0;
        #pragma unroll
        for (int k = 0; k < NSUB; ++k) s += hist[k][j];
        pb[j] = s;
    }

    // ---- last-block finalize (rocPRIM decoupled style) ----
    __threadfence();   // release: make partial stores visible device-wide
    if (tid == 0) {
        unsigned int old = atomicAdd(&counters[b * CTR_STRIDE], 1u);
        is_last = (old == (unsigned int)(blocks_per_batch - 1));
    }
    __syncthreads();

    if (is_last) {
        __threadfence();   // acquire: see all other blocks' partials
        const unsigned int* p = partial + (size_t)b * blocks_per_batch * CCP;
        for (int j = tid; j < CC; j += BLK) {      // 441 active threads
            unsigned int s = 0;
            #pragma unroll 8
            for (int r = 0; r < blocks_per_batch; ++r)
                s += p[(size_t)r * CCP + j];       // coalesced across lanes
            out[(size_t)b * CC + j] = (float)s;    // fully overwrites out
        }
    }
}

// ---------- fallback (ws too small): atomic merge ----------
__global__ __launch_bounds__(BLK, 4)
void conf_hist_atomic(const int* __restrict__ yp,
                      const int* __restrict__ y,
                      float* __restrict__ out,
                      int n_per_batch,
                      int blocks_per_batch) {
    __shared__ unsigned int hist[NSUB][CC];
    const int tid = threadIdx.x;
    for (int i = tid; i < (NSUB * CC) / 4; i += BLK)
        ((uint4*)hist)[i] = make_uint4(0u, 0u, 0u, 0u);
    __syncthreads();

    const int b   = blockIdx.x / blocks_per_batch;
    const int blk = blockIdx.x - b * blocks_per_batch;
    const int4* yp4 = (const int4*)(yp + (size_t)b * n_per_batch);
    const int4* y4  = (const int4*)(y  + (size_t)b * n_per_batch);
    const int n4 = n_per_batch >> 2;
    unsigned int* h = hist[tid >> 5];

    for (int i = blk * BLK + tid; i < n4; i += blocks_per_batch * BLK) {
        int4 a = yp4[i];
        int4 c = y4[i];
        atomicAdd(&h[a.x * C + c.x], 1u);
        atomicAdd(&h[a.y * C + c.y], 1u);
        atomicAdd(&h[a.z * C + c.z], 1u);
        atomicAdd(&h[a.w * C + c.w], 1u);
    }
    __syncthreads();

    float* ob = out + (size_t)b * CC;
    for (int j = tid; j < CC; j += BLK) {
        unsigned int s = 0;
        #pragma unroll
        for (int k = 0; k < NSUB; ++k) s += hist[k][j];
        if (s) atomicAdd(&ob[j], (float)s);
    }
}

extern "C" void kernel_launch(void* const* d_in, const int* in_sizes, int n_in,
                              void* d_out, int out_size, void* d_ws, size_t ws_size,
                              hipStream_t stream) {
    const int* yp = (const int*)d_in[0];
    const int* y  = (const int*)d_in[1];
    float* out    = (float*)d_out;

    const int total = in_sizes[0];          // B*H*W = 33,554,432
    const int B = out_size / CC;            // 8
    const int n_per_batch = total / B;      // 4,194,304

    const int blocks_per_batch = 128;       // 1024 blocks total, 4/CU x 8 waves
    const int nblocks = B * blocks_per_batch;
    const size_t ws_needed = CTR_BYTES + (size_t)nblocks * CCP * sizeof(unsigned int); // ~1.84 MB

    if (ws_size >= ws_needed && (size_t)B * CTR_STRIDE * sizeof(unsigned int) <= CTR_BYTES) {
        unsigned int* counters = (unsigned int*)d_ws;
        unsigned int* partial  = (unsigned int*)((char*)d_ws + CTR_BYTES);
        hipMemsetAsync(counters, 0, CTR_BYTES, stream);
        conf_hist_fused<<<nblocks, BLK, 0, stream>>>(
            yp, y, partial, counters, out, n_per_batch, blocks_per_batch);
    } else {
        hipMemsetAsync(out, 0, (size_t)out_size * sizeof(float), stream);
        conf_hist_atomic<<<nblocks, BLK, 0, stream>>>(
            yp, y, out, n_per_batch, blocks_per_batch);
    }
}

// Round 9
// 47.823 us; speedup vs baseline: 5.9343x; 5.9343x over previous
//
#include <hip/hip_runtime.h>

constexpr int C    = 21;
constexpr int CC   = C * C;    // 441 bins
constexpr int CCP  = 448;      // padded partial row (multiple of 64)
constexpr int NSUB = 16;       // sub-histogram per half-wave (512 thr = 16 half-waves)
constexpr int BLK  = 512;

// ---------- stage A: per-block partial histograms ----------
// GRID-STRIDE access. (R7: block-contiguous chunks regressed; R7+R8: fused
// last-block finalize with __threadfence regressed 5x -- device-scope fences
// per block throttle the whole memory system on 8-XCD MI355X. Keep two-stage.)
__global__ __launch_bounds__(BLK, 4)
void conf_hist_partial(const int* __restrict__ yp,
                       const int* __restrict__ y,
                       unsigned int* __restrict__ partial,   // [nblocks][CCP]
                       int n_per_batch,
                       int blocks_per_batch) {
    __shared__ unsigned int hist[NSUB][CC];   // 28 KiB

    const int tid = threadIdx.x;
    for (int i = tid; i < (NSUB * CC) / 4; i += BLK)
        ((uint4*)hist)[i] = make_uint4(0u, 0u, 0u, 0u);
    __syncthreads();

    const int b   = blockIdx.x / blocks_per_batch;
    const int blk = blockIdx.x - b * blocks_per_batch;

    const int4* yp4 = (const int4*)(yp + (size_t)b * n_per_batch);
    const int4* y4  = (const int4*)(y  + (size_t)b * n_per_batch);
    const int n4     = n_per_batch >> 2;
    const int stride = blocks_per_batch * BLK;

    unsigned int* h = hist[tid >> 5];   // private per half-wave

    int i = blk * BLK + tid;
    for (; i + 3 * stride < n4; i += 4 * stride) {
        int4 a0 = yp4[i];
        int4 a1 = yp4[i + stride];
        int4 a2 = yp4[i + 2 * stride];
        int4 a3 = yp4[i + 3 * stride];
        int4 c0 = y4[i];
        int4 c1 = y4[i + stride];
        int4 c2 = y4[i + 2 * stride];
        int4 c3 = y4[i + 3 * stride];

        atomicAdd(&h[a0.x * C + c0.x], 1u);
        atomicAdd(&h[a0.y * C + c0.y], 1u);
        atomicAdd(&h[a0.z * C + c0.z], 1u);
        atomicAdd(&h[a0.w * C + c0.w], 1u);
        atomicAdd(&h[a1.x * C + c1.x], 1u);
        atomicAdd(&h[a1.y * C + c1.y], 1u);
        atomicAdd(&h[a1.z * C + c1.z], 1u);
        atomicAdd(&h[a1.w * C + c1.w], 1u);
        atomicAdd(&h[a2.x * C + c2.x], 1u);
        atomicAdd(&h[a2.y * C + c2.y], 1u);
        atomicAdd(&h[a2.z * C + c2.z], 1u);
        atomicAdd(&h[a2.w * C + c2.w], 1u);
        atomicAdd(&h[a3.x * C + c3.x], 1u);
        atomicAdd(&h[a3.y * C + c3.y], 1u);
        atomicAdd(&h[a3.z * C + c3.z], 1u);
        atomicAdd(&h[a3.w * C + c3.w], 1u);
    }
    for (; i < n4; i += stride) {
        int4 a = yp4[i];
        int4 c = y4[i];
        atomicAdd(&h[a.x * C + c.x], 1u);
        atomicAdd(&h[a.y * C + c.y], 1u);
        atomicAdd(&h[a.z * C + c.z], 1u);
        atomicAdd(&h[a.w * C + c.w], 1u);
    }
    __syncthreads();

    // plain coalesced store of this block's 441 counts
    unsigned int* pb = partial + (size_t)blockIdx.x * CCP;
    for (int j = tid; j < CC; j += BLK) {
        unsigned int s = 0;
        #pragma unroll
        for (int k = 0; k < NSUB; ++k) s += hist[k][j];
        pb[j] = s;
    }
}

// ---------- stage B: parallel tiled reduce; fully overwrites out ----------
// grid = B * 7 blocks (7 groups of 64 bins cover 441), 256 threads.
__global__ __launch_bounds__(256)
void conf_finalize(const unsigned int* __restrict__ partial,
                   float* __restrict__ out,
                   int blocks_per_batch) {
    const int b    = blockIdx.x / 7;
    const int g    = blockIdx.x % 7;
    const int lane = threadIdx.x & 63;
    const int row0 = threadIdx.x >> 6;     // 0..3
    const int bin  = g * 64 + lane;

    const unsigned int* p = partial + (size_t)b * blocks_per_batch * CCP + bin;
    unsigned int acc = 0;
    #pragma unroll 8
    for (int r = row0; r < blocks_per_batch; r += 4)
        acc += p[(size_t)r * CCP];         // lanes read 64 consecutive bins: coalesced

    __shared__ unsigned int sm[4][64];
    sm[row0][lane] = acc;
    __syncthreads();

    if (threadIdx.x < 64) {
        unsigned int s = sm[0][lane] + sm[1][lane] + sm[2][lane] + sm[3][lane];
        if (bin < CC) out[(size_t)b * CC + bin] = (float)s;
    }
}

// ---------- fallback (ws too small): atomic merge ----------
__global__ __launch_bounds__(BLK, 4)
void conf_hist_atomic(const int* __restrict__ yp,
                      const int* __restrict__ y,
                      float* __restrict__ out,
                      int n_per_batch,
                      int blocks_per_batch) {
    __shared__ unsigned int hist[NSUB][CC];
    const int tid = threadIdx.x;
    for (int i = tid; i < (NSUB * CC) / 4; i += BLK)
        ((uint4*)hist)[i] = make_uint4(0u, 0u, 0u, 0u);
    __syncthreads();

    const int b   = blockIdx.x / blocks_per_batch;
    const int blk = blockIdx.x - b * blocks_per_batch;
    const int4* yp4 = (const int4*)(yp + (size_t)b * n_per_batch);
    const int4* y4  = (const int4*)(y  + (size_t)b * n_per_batch);
    const int n4 = n_per_batch >> 2;
    unsigned int* h = hist[tid >> 5];

    for (int i = blk * BLK + tid; i < n4; i += blocks_per_batch * BLK) {
        int4 a = yp4[i];
        int4 c = y4[i];
        atomicAdd(&h[a.x * C + c.x], 1u);
        atomicAdd(&h[a.y * C + c.y], 1u);
        atomicAdd(&h[a.z * C + c.z], 1u);
        atomicAdd(&h[a.w * C + c.w], 1u);
    }
    __syncthreads();

    float* ob = out + (size_t)b * CC;
    for (int j = tid; j < CC; j += BLK) {
        unsigned int s = 0;
        #pragma unroll
        for (int k = 0; k < NSUB; ++k) s += hist[k][j];
        if (s) atomicAdd(&ob[j], (float)s);
    }
}

extern "C" void kernel_launch(void* const* d_in, const int* in_sizes, int n_in,
                              void* d_out, int out_size, void* d_ws, size_t ws_size,
                              hipStream_t stream) {
    const int* yp = (const int*)d_in[0];
    const int* y  = (const int*)d_in[1];
    float* out    = (float*)d_out;

    const int total = in_sizes[0];          // B*H*W = 33,554,432
    const int B = out_size / CC;            // 8
    const int n_per_batch = total / B;      // 4,194,304

    const int blocks_per_batch = 128;       // 1024 blocks total, 4/CU x 8 waves
    const int nblocks = B * blocks_per_batch;
    const size_t ws_needed = (size_t)nblocks * CCP * sizeof(unsigned int); // ~1.84 MB

    if (ws_size >= ws_needed) {
        unsigned int* partial = (unsigned int*)d_ws;
        conf_hist_partial<<<nblocks, BLK, 0, stream>>>(
            yp, y, partial, n_per_batch, blocks_per_batch);
        conf_finalize<<<B * 7, 256, 0, stream>>>(partial, out, blocks_per_batch);
    } else {
        hipMemsetAsync(out, 0, (size_t)out_size * sizeof(float), stream);
        conf_hist_atomic<<<nblocks, BLK, 0, stream>>>(
            yp, y, out, n_per_batch, blocks_per_batch);
    }
}